// Round 1
// baseline (5112.088 us; speedup 1.0000x reference)
//
#include <hip/hip_runtime.h>
#include <hip/hip_bf16.h>
#include <cstdint>
#include <cstddef>

#define B_   32
#define T_   64
#define S_   128
#define EH   512
#define DH   512
#define ATT  256
#define EMBD 256
#define V_   32000
#define VO   31999
#define G3   1536
#define KX   1024   /* ctx(512) + h(512) */

#define ATTN_OFF 65533952   /* 32*64*31999 */

typedef __attribute__((ext_vector_type(8))) short bf16x8;
typedef __attribute__((ext_vector_type(4))) float f32x4;

static __device__ __forceinline__ unsigned short f2bf(float f) {
    union { float f; unsigned u; } x; x.f = f;
    unsigned r = (x.u + 0x7fffu + ((x.u >> 16) & 1u)) >> 16;
    return (unsigned short)r;
}

// ---------------------------------------------------------------------------
// Prep: transpose (512,256) -> (256,512) fp32   (used for W_enc and W_dec)
// grid (8,16), block (32,8)
__global__ void k_trans_512x256(const float* __restrict__ in, float* __restrict__ out) {
    __shared__ float tile[32][33];
    int c0 = blockIdx.x * 32;      // input col
    int r0 = blockIdx.y * 32;      // input row
    int tx = threadIdx.x, ty = threadIdx.y;
#pragma unroll
    for (int q = 0; q < 4; q++)
        tile[ty + q*8][tx] = in[(r0 + ty + q*8) * 256 + c0 + tx];
    __syncthreads();
#pragma unroll
    for (int q = 0; q < 4; q++)
        out[(c0 + ty + q*8) * 512 + r0 + tx] = tile[tx][ty + q*8];
}

// ---------------------------------------------------------------------------
// Prep: W_fc (512 x 31999) fp32 -> W_fcT (32000 x 512) bf16, pad row zeroed
// grid (1000,16), block (32,8)
__global__ void k_wfc(const float* __restrict__ wfc, unsigned short* __restrict__ outT) {
    __shared__ float tile[32][33];
    int n0 = blockIdx.x * 32;
    int k0 = blockIdx.y * 32;
    int tx = threadIdx.x, ty = threadIdx.y;
#pragma unroll
    for (int q = 0; q < 4; q++) {
        int k = k0 + ty + q*8;
        int n = n0 + tx;
        tile[ty + q*8][tx] = (n < VO) ? wfc[(size_t)k * VO + n] : 0.0f;
    }
    __syncthreads();
#pragma unroll
    for (int q = 0; q < 4; q++) {
        int n = n0 + ty + q*8;
        int k = k0 + tx;
        outT[(size_t)n * 512 + k] = f2bf(tile[tx][ty + q*8]);
    }
}

// ---------------------------------------------------------------------------
// Prep: pack GRU weights into MFMA B-fragment order, bf16.
// Layout: element idx = ((((j*32 + kc)*4 + q)*64 + lane)*8 + e
//   io=lane&15, ko=lane>>4, i=j*16+io, k=kc*32+ko*8+e
//   q=0: r  col (n=i):      k<512 ? W_ih[n][256+k] : W_hh[n][k-512]
//   q=1: z  col (n=512+i):  same
//   q=2: nx col (n=1024+i): k<512 ? W_ih[n][256+k] : 0
//   q=3: nh col (n=1024+i): k<512 ? 0 : W_hh[n][k-512]
// grid 8192, block 256  (2,097,152 elements)
__global__ void k_wpack(const float* __restrict__ W_ih, const float* __restrict__ W_hh,
                        unsigned short* __restrict__ Wp) {
    int idx = blockIdx.x * 256 + threadIdx.x;
    int e    = idx & 7;
    int lane = (idx >> 3) & 63;
    int q    = (idx >> 9) & 3;
    int kc   = (idx >> 11) & 31;
    int j    = idx >> 16;
    int io = lane & 15, ko = lane >> 4;
    int i = j * 16 + io;
    int k = kc * 32 + ko * 8 + e;
    int n = (q == 0) ? i : (q == 1) ? (512 + i) : (1024 + i);
    float val;
    if (k < 512) {
        val = (q == 3) ? 0.0f : W_ih[(size_t)n * 768 + 256 + k];
    } else {
        val = (q == 2) ? 0.0f : W_hh[(size_t)n * 512 + (k - 512)];
    }
    Wp[idx] = f2bf(val);
}

// ---------------------------------------------------------------------------
// Prep: h0 = decoder_init (fp32) and X0 h-half (bf16)
// grid 64, block 256
__global__ void k_hinit(const float* __restrict__ di, float* __restrict__ h0,
                        unsigned short* __restrict__ X0) {
    int idx = blockIdx.x * 256 + threadIdx.x;   // 16384
    float val = di[idx];
    h0[idx] = val;
    int b = idx >> 9, k = idx & 511;
    X0[b * KX + 512 + k] = f2bf(val);
}

// ---------------------------------------------------------------------------
// Prep: enc_proj (4096 x 256) = encoder_outputs (4096 x 512) @ W_enc
// Uses W_encT (256 x 512). Thread per col, 16 rows per block; x loads are
// block-uniform -> scalarized to s_load.
// grid 256, block 256
__global__ __launch_bounds__(256) void k_encproj(const float* __restrict__ enc,
                                                 const float* __restrict__ WencT,
                                                 float* __restrict__ ep) {
    int row0 = blockIdx.x * 16;
    int n = threadIdx.x;
    const float* wr = WencT + (size_t)n * 512;
    float acc[16];
#pragma unroll
    for (int r = 0; r < 16; r++) acc[r] = 0.0f;
    for (int k = 0; k < 512; k += 4) {
        float4 w = *(const float4*)(wr + k);
#pragma unroll
        for (int r = 0; r < 16; r++) {
            float4 x = *(const float4*)(enc + (size_t)(row0 + r) * 512 + k);
            acc[r] += x.x * w.x + x.y * w.y + x.z * w.z + x.w * w.w;
        }
    }
#pragma unroll
    for (int r = 0; r < 16; r++)
        ep[(size_t)(row0 + r) * 256 + n] = acc[r];
}

// ---------------------------------------------------------------------------
// Prep: gx_emb (2048 x 1536) = embedding[y] @ W_ih[:, :256]^T + b_ih
// W_ih native layout (1536 x 768) is [col][k] -> per-thread contiguous.
// grid (6,128), block 256
__global__ __launch_bounds__(256) void k_gxemb(const int* __restrict__ y,
                                               const float* __restrict__ embt,
                                               const float* __restrict__ W_ih,
                                               const float* __restrict__ bih,
                                               float* __restrict__ gx) {
    int row0 = blockIdx.y * 16;
    int col = blockIdx.x * 256 + threadIdx.x;
    const float* wr = W_ih + (size_t)col * 768;
    float acc[16];
#pragma unroll
    for (int r = 0; r < 16; r++) acc[r] = 0.0f;
    for (int k = 0; k < 256; k += 4) {
        float4 w = *(const float4*)(wr + k);
#pragma unroll
        for (int r = 0; r < 16; r++) {
            const float* xr = embt + (size_t)y[row0 + r] * 256 + k;  // uniform
            float4 x = *(const float4*)xr;
            acc[r] += x.x * w.x + x.y * w.y + x.z * w.z + x.w * w.w;
        }
    }
    float bv = bih[col];
#pragma unroll
    for (int r = 0; r < 16; r++)
        gx[(size_t)(row0 + r) * G3 + col] = acc[r] + bv;
}

// ---------------------------------------------------------------------------
// Per-step attention: dec-proj, energy (tanh . v), masked softmax, context.
// One block per batch element. Writes attention weights (output 1) and the
// bf16 context into X[t&1]'s ctx half.
// grid 32, block 256
__global__ __launch_bounds__(256) void k_att(const float* __restrict__ h,
                                             const float* __restrict__ WdecT,
                                             const float* __restrict__ ep,
                                             const float* __restrict__ v,
                                             const int* __restrict__ mask,
                                             const float* __restrict__ enc,
                                             float* __restrict__ attn_out,
                                             unsigned short* __restrict__ Xc,
                                             int t) {
    __shared__ float dec_s[256];
    __shared__ float es[128];
    __shared__ float red[2];
    int b = blockIdx.x, tid = threadIdx.x;

    // dec = h[b] @ W_dec  (h loads uniform -> scalar)
    {
        float acc = 0.0f;
        const float* wr = WdecT + (size_t)tid * 512;
        const float* hb = h + (size_t)b * 512;
        for (int k = 0; k < 512; k += 4) {
            float4 w = *(const float4*)(wr + k);
            float4 x = *(const float4*)(hb + k);
            acc += x.x * w.x + x.y * w.y + x.z * w.z + x.w * w.w;
        }
        dec_s[tid] = acc;
    }
    __syncthreads();

    int wv = tid >> 6, lane = tid & 63;
    // energy[s] = sum_k tanh(ep[b,s,k] + dec[k]) * v[k]
    {
        float d0 = dec_s[lane], d1 = dec_s[lane + 64], d2 = dec_s[lane + 128], d3 = dec_s[lane + 192];
        float v0 = v[lane], v1 = v[lane + 64], v2 = v[lane + 128], v3 = v[lane + 192];
        for (int s = wv; s < 128; s += 4) {
            const float* er = ep + (size_t)(b * 128 + s) * 256;
            float e = tanhf(er[lane] + d0) * v0
                    + tanhf(er[lane + 64] + d1) * v1
                    + tanhf(er[lane + 128] + d2) * v2
                    + tanhf(er[lane + 192] + d3) * v3;
#pragma unroll
            for (int o = 32; o; o >>= 1) e += __shfl_xor(e, o);
            if (lane == 0)
                es[s] = (mask[b * 128 + s] == 0) ? -1e9f : e;
        }
    }
    __syncthreads();
    // softmax over 128
    if (tid < 64) {
        float a = fmaxf(es[tid], es[tid + 64]);
#pragma unroll
        for (int o = 32; o; o >>= 1) a = fmaxf(a, __shfl_xor(a, o));
        if (tid == 0) red[0] = a;
    }
    __syncthreads();
    float mx = red[0];
    if (tid < 128) es[tid] = __expf(es[tid] - mx);
    __syncthreads();
    if (tid < 64) {
        float a = es[tid] + es[tid + 64];
#pragma unroll
        for (int o = 32; o; o >>= 1) a += __shfl_xor(a, o);
        if (tid == 0) red[1] = a;
    }
    __syncthreads();
    float inv = 1.0f / red[1];
    if (tid < 128) {
        float aw = es[tid] * inv;
        es[tid] = aw;
        attn_out[(size_t)b * (T_ * S_) + t * S_ + tid] = aw;
    }
    __syncthreads();
    // context = aw @ encoder_outputs  (dims tid and tid+256)
    {
        float a1 = 0.0f, a2 = 0.0f;
        for (int s = 0; s < 128; s++) {
            float a = es[s];
            const float* er = enc + (size_t)(b * 128 + s) * 512;
            a1 += a * er[tid];
            a2 += a * er[tid + 256];
        }
        Xc[b * KX + tid] = f2bf(a1);
        Xc[b * KX + tid + 256] = f2bf(a2);
    }
}

// ---------------------------------------------------------------------------
// Per-step GRU: gates = [ctx|h] @ W' via MFMA, lane-local gating, write h.
// grid 8, block 512 (8 waves). wave gw = bid*8+w: j = gw>>1 (0..31), mt = gw&1.
__global__ __launch_bounds__(512) void k_gru(const unsigned short* __restrict__ X,
                                             const unsigned short* __restrict__ Wp,
                                             const float* __restrict__ gx_emb,
                                             const float* __restrict__ b_hh,
                                             const float* __restrict__ h_prev,
                                             float* __restrict__ h_next,
                                             unsigned short* __restrict__ X_next,
                                             unsigned short* __restrict__ H_all,
                                             int t) {
    __shared__ unsigned short Xs[32 * 1032];   // rows padded to 1032 bf16 = 2064 B
    int tid = threadIdx.x;
    {
        const uint4* Xg = (const uint4*)X;
        for (int e = tid; e < 4096; e += 512) {
            int r = e >> 7, c = e & 127;
            *(uint4*)((char*)Xs + r * 2064 + c * 16) = Xg[e];
        }
    }
    __syncthreads();

    int w = tid >> 6, lane = tid & 63;
    int gw = blockIdx.x * 8 + w;
    int j = gw >> 1, mt = gw & 1;
    int io = lane & 15, ko = lane >> 4;

    const char* ab = (const char*)Xs + (size_t)(mt * 16 + io) * 2064 + ko * 16;
    const uint4* bb = (const uint4*)Wp + ((size_t)j << 13) + lane;  // 8192 uint4 per j

    f32x4 z4 = {0.f, 0.f, 0.f, 0.f};
    f32x4 acc0 = z4, acc1 = z4, acc2 = z4, acc3 = z4;

    bf16x8 a0 = *(const bf16x8*)ab;
    uint4 q0 = bb[0], q1 = bb[64], q2 = bb[128], q3 = bb[192];

#pragma unroll
    for (int kc = 0; kc < 32; kc++) {
        bf16x8 an; uint4 n0, n1, n2, n3;
        if (kc < 31) {
            an = *(const bf16x8*)(ab + (kc + 1) * 64);
            const uint4* bn = bb + (size_t)(kc + 1) * 256;
            n0 = bn[0]; n1 = bn[64]; n2 = bn[128]; n3 = bn[192];
        }
        acc0 = __builtin_amdgcn_mfma_f32_16x16x32_bf16(a0, *(const bf16x8*)&q0, acc0, 0, 0, 0);
        acc1 = __builtin_amdgcn_mfma_f32_16x16x32_bf16(a0, *(const bf16x8*)&q1, acc1, 0, 0, 0);
        acc2 = __builtin_amdgcn_mfma_f32_16x16x32_bf16(a0, *(const bf16x8*)&q2, acc2, 0, 0, 0);
        acc3 = __builtin_amdgcn_mfma_f32_16x16x32_bf16(a0, *(const bf16x8*)&q3, acc3, 0, 0, 0);
        if (kc < 31) { a0 = an; q0 = n0; q1 = n1; q2 = n2; q3 = n3; }
    }

    // gating: lane-local (C layout: col=lane&15 -> i, row=ko*4+reg -> b)
    int i = j * 16 + io;
    float bh_r = b_hh[i], bh_z = b_hh[512 + i], bh_n = b_hh[1024 + i];
#pragma unroll
    for (int reg = 0; reg < 4; reg++) {
        int b = mt * 16 + ko * 4 + reg;
        int m = b * 64 + t;
        const float* ge = gx_emb + (size_t)m * G3;
        float xr = ge[i] + acc0[reg] + bh_r;
        float xz = ge[512 + i] + acc1[reg] + bh_z;
        float r = 1.0f / (1.0f + __expf(-xr));
        float z = 1.0f / (1.0f + __expf(-xz));
        float hn = acc3[reg] + bh_n;
        float n = tanhf(ge[1024 + i] + acc2[reg] + r * hn);
        float prev = h_prev[(size_t)b * 512 + i];
        float hv = (1.0f - z) * n + z * prev;
        h_next[(size_t)b * 512 + i] = hv;
        X_next[b * KX + 512 + i] = f2bf(hv);
        H_all[(size_t)m * 512 + i] = f2bf(hv);
    }
}

// ---------------------------------------------------------------------------
// FC: out (2048 x 31999) = H_all (2048x512) bf16 @ W_fcT^T bf16 + b_fc
// 128x128 tiles, BK=32, 4 waves (2x2), each wave 64x64 (4x4 MFMA tiles).
// LDS rows padded to 80 B (conflict-free frag reads, 16B-aligned writes).
// grid (250,16), block 256
__global__ __launch_bounds__(256) void k_fc(const unsigned short* __restrict__ A,
                                            const unsigned short* __restrict__ Bt,
                                            const float* __restrict__ bias,
                                            float* __restrict__ out) {
    __shared__ unsigned short Abuf[128 * 40];
    __shared__ unsigned short Bbuf[128 * 40];
    int tid = threadIdx.x;
    int n0 = blockIdx.x * 128, m0 = blockIdx.y * 128;
    int w = tid >> 6, lane = tid & 63;
    int wm = w >> 1, wn = w & 1;
    int io = lane & 15, ko = lane >> 4;

    const uint4* Ag = (const uint4*)A;     // row = 64 uint4
    const uint4* Bg = (const uint4*)Bt;

    f32x4 z4 = {0.f, 0.f, 0.f, 0.f};
    f32x4 acc[4][4];
#pragma unroll
    for (int a = 0; a < 4; a++)
#pragma unroll
        for (int b = 0; b < 4; b++) acc[a][b] = z4;

    for (int k0 = 0; k0 < 512; k0 += 32) {
        uint4 av[2], bv[2];
#pragma unroll
        for (int u = 0; u < 2; u++) {
            int c = tid + u * 256;
            int r = c >> 2, ch = c & 3;
            av[u] = Ag[(size_t)(m0 + r) * 64 + (k0 >> 3) + ch];
            bv[u] = Bg[(size_t)(n0 + r) * 64 + (k0 >> 3) + ch];
        }
        __syncthreads();
#pragma unroll
        for (int u = 0; u < 2; u++) {
            int c = tid + u * 256;
            int r = c >> 2, ch = c & 3;
            *(uint4*)((char*)Abuf + r * 80 + ch * 16) = av[u];
            *(uint4*)((char*)Bbuf + r * 80 + ch * 16) = bv[u];
        }
        __syncthreads();
        bf16x8 af[4], bf[4];
#pragma unroll
        for (int s = 0; s < 4; s++) {
            af[s] = *(const bf16x8*)((char*)Abuf + (wm * 64 + s * 16 + io) * 80 + ko * 16);
            bf[s] = *(const bf16x8*)((char*)Bbuf + (wn * 64 + s * 16 + io) * 80 + ko * 16);
        }
#pragma unroll
        for (int sm = 0; sm < 4; sm++)
#pragma unroll
            for (int sn = 0; sn < 4; sn++)
                acc[sm][sn] = __builtin_amdgcn_mfma_f32_16x16x32_bf16(af[sm], bf[sn], acc[sm][sn], 0, 0, 0);
    }

#pragma unroll
    for (int sm = 0; sm < 4; sm++)
#pragma unroll
        for (int sn = 0; sn < 4; sn++) {
            int ng = n0 + wn * 64 + sn * 16 + io;
            if (ng < VO) {
                float bvv = bias[ng];
#pragma unroll
                for (int reg = 0; reg < 4; reg++) {
                    int mg = m0 + wm * 64 + sm * 16 + ko * 4 + reg;
                    out[(size_t)mg * VO + ng] = acc[sm][sn][reg] + bvv;
                }
            }
        }
}

// ---------------------------------------------------------------------------
extern "C" void kernel_launch(void* const* d_in, const int* in_sizes, int n_in,
                              void* d_out, int out_size, void* d_ws, size_t ws_size,
                              hipStream_t stream) {
    const int*   y      = (const int*)d_in[0];
    const float* enc    = (const float*)d_in[1];
    const float* dinit  = (const float*)d_in[2];
    const int*   mask   = (const int*)d_in[3];
    const float* embt   = (const float*)d_in[4];
    const float* W_enc  = (const float*)d_in[5];
    const float* W_dec  = (const float*)d_in[6];
    const float* v      = (const float*)d_in[7];
    const float* W_ih   = (const float*)d_in[8];
    const float* W_hh   = (const float*)d_in[9];
    const float* b_ih   = (const float*)d_in[10];
    const float* b_hh   = (const float*)d_in[11];
    const float* W_fc   = (const float*)d_in[12];
    const float* b_fc   = (const float*)d_in[13];
    float* out = (float*)d_out;

    char* ws = (char*)d_ws;
    size_t o = 0;
    float* enc_proj = (float*)(ws + o);          o += (size_t)4096 * 256 * 4;       // 4,194,304
    float* gx_emb   = (float*)(ws + o);          o += (size_t)2048 * 1536 * 4;      // 12,582,912
    float* WencT    = (float*)(ws + o);          o += (size_t)256 * 512 * 4;        // 524,288
    float* WdecT    = (float*)(ws + o);          o += (size_t)256 * 512 * 4;        // 524,288
    unsigned short* Wp   = (unsigned short*)(ws + o); o += (size_t)2097152 * 2;     // 4,194,304
    unsigned short* WfcT = (unsigned short*)(ws + o); o += (size_t)32000 * 512 * 2; // 32,768,000
    unsigned short* Hall = (unsigned short*)(ws + o); o += (size_t)2048 * 512 * 2;  // 2,097,152
    unsigned short* X0   = (unsigned short*)(ws + o); o += (size_t)32 * KX * 2;     // 65,536
    unsigned short* X1   = (unsigned short*)(ws + o); o += (size_t)32 * KX * 2;
    float* h32a = (float*)(ws + o);              o += (size_t)32 * 512 * 4;
    float* h32b = (float*)(ws + o);              o += (size_t)32 * 512 * 4;

    // --- prep ---
    k_trans_512x256<<<dim3(8, 16), dim3(32, 8), 0, stream>>>(W_enc, WencT);
    k_trans_512x256<<<dim3(8, 16), dim3(32, 8), 0, stream>>>(W_dec, WdecT);
    k_wfc<<<dim3(1000, 16), dim3(32, 8), 0, stream>>>(W_fc, WfcT);
    k_wpack<<<8192, 256, 0, stream>>>(W_ih, W_hh, Wp);
    k_hinit<<<64, 256, 0, stream>>>(dinit, h32a, X0);
    k_encproj<<<256, 256, 0, stream>>>(enc, WencT, enc_proj);
    k_gxemb<<<dim3(6, 128), 256, 0, stream>>>(y, embt, W_ih, b_ih, gx_emb);

    float* attn_out = out + ATTN_OFF;

    // --- recurrence ---
    for (int t = 0; t < T_; t++) {
        unsigned short* cur = (t & 1) ? X1 : X0;
        unsigned short* nxt = (t & 1) ? X0 : X1;
        float* hp = (t & 1) ? h32b : h32a;
        float* hn = (t & 1) ? h32a : h32b;
        k_att<<<32, 256, 0, stream>>>(hp, WdecT, enc_proj, v, mask, enc, attn_out, cur, t);
        k_gru<<<8, 512, 0, stream>>>(cur, Wp, gx_emb, b_hh, hp, hn, nxt, Hall, t);
    }

    // --- batched FC over all (b,t) ---
    k_fc<<<dim3(250, 16), 256, 0, stream>>>(Hall, WfcT, b_fc, out);
}

// Round 2
// 3911.900 us; speedup vs baseline: 1.3068x; 1.3068x over previous
//
#include <hip/hip_runtime.h>
#include <hip/hip_bf16.h>
#include <hip/hip_cooperative_groups.h>
#include <cstdint>
#include <cstddef>

namespace cg = cooperative_groups;

#define B_   32
#define T_   64
#define S_   128
#define EH   512
#define DH   512
#define ATT  256
#define EMBD 256
#define V_   32000
#define VO   31999
#define G3   1536
#define KX   1024   /* ctx(512) + h(512) */

#define ATTN_OFF 65533952   /* 32*64*31999 */

typedef __attribute__((ext_vector_type(8))) short bf16x8;
typedef __attribute__((ext_vector_type(4))) float f32x4;

static __device__ __forceinline__ unsigned short f2bf(float f) {
    union { float f; unsigned u; } x; x.f = f;
    unsigned r = (x.u + 0x7fffu + ((x.u >> 16) & 1u)) >> 16;
    return (unsigned short)r;
}

static __device__ __forceinline__ float fast_tanh(float x) {
    float xc = fminf(fmaxf(x, -15.0f), 15.0f);
    float e = __expf(2.0f * xc);
    return (e - 1.0f) / (e + 1.0f);
}

static __device__ __forceinline__ float fast_sig(float x) {
    return 1.0f / (1.0f + __expf(-x));
}

// ---------------------------------------------------------------------------
// Prep: transpose (512,256) -> (256,512) fp32   (used for W_enc and W_dec)
__global__ void k_trans_512x256(const float* __restrict__ in, float* __restrict__ out) {
    __shared__ float tile[32][33];
    int c0 = blockIdx.x * 32;
    int r0 = blockIdx.y * 32;
    int tx = threadIdx.x, ty = threadIdx.y;
#pragma unroll
    for (int q = 0; q < 4; q++)
        tile[ty + q*8][tx] = in[(r0 + ty + q*8) * 256 + c0 + tx];
    __syncthreads();
#pragma unroll
    for (int q = 0; q < 4; q++)
        out[(c0 + ty + q*8) * 512 + r0 + tx] = tile[tx][ty + q*8];
}

// ---------------------------------------------------------------------------
// Prep: W_fc (512 x 31999) fp32 -> W_fcT (32000 x 512) bf16, pad row zeroed
__global__ void k_wfc(const float* __restrict__ wfc, unsigned short* __restrict__ outT) {
    __shared__ float tile[32][33];
    int n0 = blockIdx.x * 32;
    int k0 = blockIdx.y * 32;
    int tx = threadIdx.x, ty = threadIdx.y;
#pragma unroll
    for (int q = 0; q < 4; q++) {
        int k = k0 + ty + q*8;
        int n = n0 + tx;
        tile[ty + q*8][tx] = (n < VO) ? wfc[(size_t)k * VO + n] : 0.0f;
    }
    __syncthreads();
#pragma unroll
    for (int q = 0; q < 4; q++) {
        int n = n0 + ty + q*8;
        int k = k0 + tx;
        outT[(size_t)n * 512 + k] = f2bf(tile[tx][ty + q*8]);
    }
}

// ---------------------------------------------------------------------------
// Prep: pack GRU weights into MFMA B-fragment order, bf16.
// idx = (((j*32 + kc)*4 + q)*64 + lane)*8 + e
__global__ void k_wpack(const float* __restrict__ W_ih, const float* __restrict__ W_hh,
                        unsigned short* __restrict__ Wp) {
    int idx = blockIdx.x * 256 + threadIdx.x;
    int e    = idx & 7;
    int lane = (idx >> 3) & 63;
    int q    = (idx >> 9) & 3;
    int kc   = (idx >> 11) & 31;
    int j    = idx >> 16;
    int io = lane & 15, ko = lane >> 4;
    int i = j * 16 + io;
    int k = kc * 32 + ko * 8 + e;
    int n = (q == 0) ? i : (q == 1) ? (512 + i) : (1024 + i);
    float val;
    if (k < 512) {
        val = (q == 3) ? 0.0f : W_ih[(size_t)n * 768 + 256 + k];
    } else {
        val = (q == 2) ? 0.0f : W_hh[(size_t)n * 512 + (k - 512)];
    }
    Wp[idx] = f2bf(val);
}

// ---------------------------------------------------------------------------
// Prep: h0 = decoder_init (fp32) and X0 h-half (bf16)
__global__ void k_hinit(const float* __restrict__ di, float* __restrict__ h0,
                        unsigned short* __restrict__ X0) {
    int idx = blockIdx.x * 256 + threadIdx.x;   // 16384
    float val = di[idx];
    h0[idx] = val;
    int b = idx >> 9, k = idx & 511;
    X0[b * KX + 512 + k] = f2bf(val);
}

// ---------------------------------------------------------------------------
// Prep: enc_proj (4096 x 256) = encoder_outputs (4096 x 512) @ W_enc
__global__ __launch_bounds__(256) void k_encproj(const float* __restrict__ enc,
                                                 const float* __restrict__ WencT,
                                                 float* __restrict__ ep) {
    int row0 = blockIdx.x * 16;
    int n = threadIdx.x;
    const float* wr = WencT + (size_t)n * 512;
    float acc[16];
#pragma unroll
    for (int r = 0; r < 16; r++) acc[r] = 0.0f;
    for (int k = 0; k < 512; k += 4) {
        float4 w = *(const float4*)(wr + k);
#pragma unroll
        for (int r = 0; r < 16; r++) {
            float4 x = *(const float4*)(enc + (size_t)(row0 + r) * 512 + k);
            acc[r] += x.x * w.x + x.y * w.y + x.z * w.z + x.w * w.w;
        }
    }
#pragma unroll
    for (int r = 0; r < 16; r++)
        ep[(size_t)(row0 + r) * 256 + n] = acc[r];
}

// ---------------------------------------------------------------------------
// Prep: gx_emb (2048 x 1536) = embedding[y] @ W_ih[:, :256]^T + b_ih
__global__ __launch_bounds__(256) void k_gxemb(const int* __restrict__ y,
                                               const float* __restrict__ embt,
                                               const float* __restrict__ W_ih,
                                               const float* __restrict__ bih,
                                               float* __restrict__ gx) {
    int row0 = blockIdx.y * 16;
    int col = blockIdx.x * 256 + threadIdx.x;
    const float* wr = W_ih + (size_t)col * 768;
    float acc[16];
#pragma unroll
    for (int r = 0; r < 16; r++) acc[r] = 0.0f;
    for (int k = 0; k < 256; k += 4) {
        float4 w = *(const float4*)(wr + k);
#pragma unroll
        for (int r = 0; r < 16; r++) {
            const float* xr = embt + (size_t)y[row0 + r] * 256 + k;  // uniform
            float4 x = *(const float4*)xr;
            acc[r] += x.x * w.x + x.y * w.y + x.z * w.z + x.w * w.w;
        }
    }
    float bv = bih[col];
#pragma unroll
    for (int r = 0; r < 16; r++)
        gx[(size_t)(row0 + r) * G3 + col] = acc[r] + bv;
}

// ---------------------------------------------------------------------------
// Persistent cooperative kernel: runs all 64 decode steps.
// Grid 64 x 512. Blocks 0..31: attention for batch b = blockIdx.x.
// All 64 blocks: GRU tile (j = bid>>1, mt = bid&1); K split over 8 waves
// (wave w: gate q = w&3, K-half kh = w>>2), partial accs reduced in LDS.
__global__ __launch_bounds__(512) void k_persist(
        const float* __restrict__ WdecT, const float* __restrict__ ep,
        const float* __restrict__ v, const int* __restrict__ mask,
        const float* __restrict__ enc, float* __restrict__ attn_out,
        const unsigned short* __restrict__ Wp, const float* __restrict__ gx_emb,
        const float* __restrict__ b_hh, unsigned short* __restrict__ X0,
        unsigned short* __restrict__ X1, float* __restrict__ h32a,
        float* __restrict__ h32b, unsigned short* __restrict__ Hall) {
    __shared__ char As[16 * 2064];     // GRU A-stage: 16 rows x 1024 bf16 (+pad)
    __shared__ float pacc[2048];       // 8 waves x 16x16 partial C
    __shared__ float decp[512];
    __shared__ float es[128];
    __shared__ float red[2];

    cg::grid_group grid = cg::this_grid();

    int bid = blockIdx.x, tid = threadIdx.x;
    int w = tid >> 6, lane = tid & 63;
    int io = lane & 15, ko = lane >> 4;
    int j = bid >> 1, mt = bid & 1;
    int q = w & 3, kh = w >> 2;

    for (int t = 0; t < T_; t++) {
        unsigned short* Xp = (t & 1) ? X1 : X0;
        unsigned short* Xq = (t & 1) ? X0 : X1;
        const float* hp = (t & 1) ? h32b : h32a;
        float* hn = (t & 1) ? h32a : h32b;

        // ---------------- Phase A: attention (blocks 0..31) ----------------
        if (bid < 32) {
            int b = bid;
            // dec = h[b] @ W_dec, split K across thread halves
            {
                int d = tid & 255, half = tid >> 8;
                const float* wr = WdecT + (size_t)d * 512 + half * 256;
                const float* hb = hp + (size_t)b * 512 + half * 256;
                float acc = 0.0f;
#pragma unroll 8
                for (int k = 0; k < 256; k += 4) {
                    float4 wv = *(const float4*)(wr + k);
                    float4 xv = *(const float4*)(hb + k);
                    acc += xv.x * wv.x + xv.y * wv.y + xv.z * wv.z + xv.w * wv.w;
                }
                decp[tid] = acc;
            }
            __syncthreads();
            if (tid < 256) decp[tid] += decp[tid + 256];
            __syncthreads();
            // energy: wave w handles s = w*16 .. w*16+15
            {
                float d0 = decp[lane], d1 = decp[lane + 64],
                      d2 = decp[lane + 128], d3 = decp[lane + 192];
                float v0 = v[lane], v1 = v[lane + 64],
                      v2 = v[lane + 128], v3 = v[lane + 192];
#pragma unroll
                for (int si = 0; si < 16; si++) {
                    int s = w * 16 + si;
                    const float* er = ep + (size_t)(b * 128 + s) * 256;
                    float e = fast_tanh(er[lane] + d0) * v0
                            + fast_tanh(er[lane + 64] + d1) * v1
                            + fast_tanh(er[lane + 128] + d2) * v2
                            + fast_tanh(er[lane + 192] + d3) * v3;
#pragma unroll
                    for (int o = 32; o; o >>= 1) e += __shfl_xor(e, o);
                    if (lane == 0)
                        es[s] = (mask[b * 128 + s] == 0) ? -1e9f : e;
                }
            }
            __syncthreads();
            if (tid < 64) {
                float a = fmaxf(es[tid], es[tid + 64]);
#pragma unroll
                for (int o = 32; o; o >>= 1) a = fmaxf(a, __shfl_xor(a, o));
                if (tid == 0) red[0] = a;
            }
            __syncthreads();
            float mx = red[0];
            if (tid < 128) es[tid] = __expf(es[tid] - mx);
            __syncthreads();
            if (tid < 64) {
                float a = es[tid] + es[tid + 64];
#pragma unroll
                for (int o = 32; o; o >>= 1) a += __shfl_xor(a, o);
                if (tid == 0) red[1] = a;
            }
            __syncthreads();
            float inv = 1.0f / red[1];
            if (tid < 128) {
                float aw = es[tid] * inv;
                es[tid] = aw;
                attn_out[(size_t)b * (T_ * S_) + t * S_ + tid] = aw;
            }
            __syncthreads();
            // context: thread d = tid over 512 dims
            {
                float a1 = 0.0f;
                const float* eb = enc + (size_t)b * 128 * 512 + tid;
#pragma unroll 8
                for (int s = 0; s < 128; s++)
                    a1 += es[s] * eb[(size_t)s * 512];
                Xp[b * KX + tid] = f2bf(a1);
            }
        }
        grid.sync();

        // ---------------- Phase B: GRU (all 64 blocks) ----------------
        // stage A rows (16 x 1024 bf16) for this mt
        {
            const uint4* Xg = (const uint4*)Xp + mt * 16 * 128;
#pragma unroll
            for (int e = 0; e < 4; e++) {
                int idx = tid + e * 512;
                int r = idx >> 7, c = idx & 127;
                *(uint4*)(As + r * 2064 + c * 16) = Xg[idx];
            }
        }
        __syncthreads();
        // MFMA: wave w -> gate q, K-half kh (16 kc chunks)
        {
            const uint4* bb = (const uint4*)Wp + ((size_t)j << 13) + q * 64 + lane;
            const char* ab = As + io * 2064 + ko * 16;
            f32x4 acc = {0.f, 0.f, 0.f, 0.f};
#pragma unroll
            for (int kc2 = 0; kc2 < 16; kc2++) {
                int kc = kh * 16 + kc2;
                bf16x8 a = *(const bf16x8*)(ab + kc * 64);
                uint4 bq = bb[kc * 256];
                acc = __builtin_amdgcn_mfma_f32_16x16x32_bf16(a, *(const bf16x8*)&bq, acc, 0, 0, 0);
            }
#pragma unroll
            for (int reg = 0; reg < 4; reg++)
                pacc[w * 256 + (ko * 4 + reg) * 16 + io] = acc[reg];
        }
        __syncthreads();
        // gating: 256 threads, lane-local
        if (tid < 256) {
            int i2 = tid & 15, b2 = tid >> 4;
            float rp = pacc[tid]       + pacc[1024 + tid];
            float zp = pacc[256 + tid] + pacc[1280 + tid];
            float nx = pacc[512 + tid] + pacc[1536 + tid];
            float nh = pacc[768 + tid] + pacc[1792 + tid];
            int i = j * 16 + i2, b = mt * 16 + b2, m = b * 64 + t;
            const float* ge = gx_emb + (size_t)m * G3;
            float r = fast_sig(ge[i] + rp + b_hh[i]);
            float z = fast_sig(ge[512 + i] + zp + b_hh[512 + i]);
            float n = fast_tanh(ge[1024 + i] + nx + r * (nh + b_hh[1024 + i]));
            float prev = hp[(size_t)b * 512 + i];
            float hv = (1.0f - z) * n + z * prev;
            hn[(size_t)b * 512 + i] = hv;
            Xq[b * KX + 512 + i] = f2bf(hv);
            Hall[(size_t)m * 512 + i] = f2bf(hv);
        }
        grid.sync();
    }
}

// ---------------------------------------------------------------------------
// FC: out (2048 x 31999) = H_all (2048x512) bf16 @ W_fcT^T bf16 + b_fc
// 128x128 tiles, BK=32. Epilogue stages C in LDS and writes contiguous rows
// (512 B/row) to avoid partial-line RMW write amplification.
__global__ __launch_bounds__(256) void k_fc(const unsigned short* __restrict__ A,
                                            const unsigned short* __restrict__ Bt,
                                            const float* __restrict__ bias,
                                            float* __restrict__ out) {
    __shared__ char smem[65536];
    unsigned short* Abuf = (unsigned short*)smem;            // 128*40 = 10240 B
    unsigned short* Bbuf = (unsigned short*)(smem + 10240);  // 10240 B
    int tid = threadIdx.x;
    int n0 = blockIdx.x * 128, m0 = blockIdx.y * 128;
    int w = tid >> 6, lane = tid & 63;
    int wm = w >> 1, wn = w & 1;
    int io = lane & 15, ko = lane >> 4;

    const uint4* Ag = (const uint4*)A;
    const uint4* Bg = (const uint4*)Bt;

    f32x4 z4 = {0.f, 0.f, 0.f, 0.f};
    f32x4 acc[4][4];
#pragma unroll
    for (int a = 0; a < 4; a++)
#pragma unroll
        for (int b = 0; b < 4; b++) acc[a][b] = z4;

    for (int k0 = 0; k0 < 512; k0 += 32) {
        uint4 av[2], bv[2];
#pragma unroll
        for (int u = 0; u < 2; u++) {
            int c = tid + u * 256;
            int r = c >> 2, ch = c & 3;
            av[u] = Ag[(size_t)(m0 + r) * 64 + (k0 >> 3) + ch];
            bv[u] = Bg[(size_t)(n0 + r) * 64 + (k0 >> 3) + ch];
        }
        __syncthreads();
#pragma unroll
        for (int u = 0; u < 2; u++) {
            int c = tid + u * 256;
            int r = c >> 2, ch = c & 3;
            *(uint4*)((char*)Abuf + r * 80 + ch * 16) = av[u];
            *(uint4*)((char*)Bbuf + r * 80 + ch * 16) = bv[u];
        }
        __syncthreads();
        bf16x8 af[4], bf[4];
#pragma unroll
        for (int s = 0; s < 4; s++) {
            af[s] = *(const bf16x8*)((char*)Abuf + (wm * 64 + s * 16 + io) * 80 + ko * 16);
            bf[s] = *(const bf16x8*)((char*)Bbuf + (wn * 64 + s * 16 + io) * 80 + ko * 16);
        }
#pragma unroll
        for (int sm = 0; sm < 4; sm++)
#pragma unroll
            for (int sn = 0; sn < 4; sn++)
                acc[sm][sn] = __builtin_amdgcn_mfma_f32_16x16x32_bf16(af[sm], bf[sn], acc[sm][sn], 0, 0, 0);
    }

    __syncthreads();
    float* Cst = (float*)smem;   // 128 x 128 fp32 = 64 KB
#pragma unroll
    for (int sm = 0; sm < 4; sm++)
#pragma unroll
        for (int sn = 0; sn < 4; sn++) {
            int cc = wn * 64 + sn * 16 + io;
#pragma unroll
            for (int reg = 0; reg < 4; reg++) {
                int rr = wm * 64 + sm * 16 + ko * 4 + reg;
                Cst[rr * 128 + cc] = acc[sm][sn][reg];
            }
        }
    __syncthreads();
    {
        int c = tid & 127, rh = tid >> 7;
        int ng = n0 + c;
        if (ng < VO) {
            float bv = bias[ng];
#pragma unroll 8
            for (int i = 0; i < 64; i++) {
                int r = i * 2 + rh;
                out[(size_t)(m0 + r) * VO + ng] = Cst[r * 128 + c] + bv;
            }
        }
    }
}

// ---------------------------------------------------------------------------
extern "C" void kernel_launch(void* const* d_in, const int* in_sizes, int n_in,
                              void* d_out, int out_size, void* d_ws, size_t ws_size,
                              hipStream_t stream) {
    const int*   y      = (const int*)d_in[0];
    const float* enc    = (const float*)d_in[1];
    const float* dinit  = (const float*)d_in[2];
    const int*   mask   = (const int*)d_in[3];
    const float* embt   = (const float*)d_in[4];
    const float* W_enc  = (const float*)d_in[5];
    const float* W_dec  = (const float*)d_in[6];
    const float* v      = (const float*)d_in[7];
    const float* W_ih   = (const float*)d_in[8];
    const float* W_hh   = (const float*)d_in[9];
    const float* b_ih   = (const float*)d_in[10];
    const float* b_hh   = (const float*)d_in[11];
    const float* W_fc   = (const float*)d_in[12];
    const float* b_fc   = (const float*)d_in[13];
    float* out = (float*)d_out;

    char* ws = (char*)d_ws;
    size_t o = 0;
    float* enc_proj = (float*)(ws + o);          o += (size_t)4096 * 256 * 4;
    float* gx_emb   = (float*)(ws + o);          o += (size_t)2048 * 1536 * 4;
    float* WencT    = (float*)(ws + o);          o += (size_t)256 * 512 * 4;
    float* WdecT    = (float*)(ws + o);          o += (size_t)256 * 512 * 4;
    unsigned short* Wp   = (unsigned short*)(ws + o); o += (size_t)2097152 * 2;
    unsigned short* WfcT = (unsigned short*)(ws + o); o += (size_t)32000 * 512 * 2;
    unsigned short* Hall = (unsigned short*)(ws + o); o += (size_t)2048 * 512 * 2;
    unsigned short* X0   = (unsigned short*)(ws + o); o += (size_t)32 * KX * 2;
    unsigned short* X1   = (unsigned short*)(ws + o); o += (size_t)32 * KX * 2;
    float* h32a = (float*)(ws + o);              o += (size_t)32 * 512 * 4;
    float* h32b = (float*)(ws + o);              o += (size_t)32 * 512 * 4;

    // --- prep ---
    k_trans_512x256<<<dim3(8, 16), dim3(32, 8), 0, stream>>>(W_enc, WencT);
    k_trans_512x256<<<dim3(8, 16), dim3(32, 8), 0, stream>>>(W_dec, WdecT);
    k_wfc<<<dim3(1000, 16), dim3(32, 8), 0, stream>>>(W_fc, WfcT);
    k_wpack<<<8192, 256, 0, stream>>>(W_ih, W_hh, Wp);
    k_hinit<<<64, 256, 0, stream>>>(dinit, h32a, X0);
    k_encproj<<<256, 256, 0, stream>>>(enc, WencT, enc_proj);
    k_gxemb<<<dim3(6, 128), 256, 0, stream>>>(y, embt, W_ih, b_ih, gx_emb);

    float* attn_out = out + ATTN_OFF;

    // --- recurrence: one persistent cooperative kernel ---
    {
        const float* WdecT_c = WdecT; const float* ep_c = enc_proj;
        const unsigned short* Wp_c = Wp; const float* gx_c = gx_emb;
        void* args[] = {
            (void*)&WdecT_c, (void*)&ep_c, (void*)&v, (void*)&mask,
            (void*)&enc, (void*)&attn_out, (void*)&Wp_c, (void*)&gx_c,
            (void*)&b_hh, (void*)&X0, (void*)&X1, (void*)&h32a,
            (void*)&h32b, (void*)&Hall
        };
        hipLaunchCooperativeKernel((void*)k_persist, dim3(64), dim3(512),
                                   args, 0, stream);
    }

    // --- batched FC over all (b,t) ---
    k_fc<<<dim3(250, 16), 256, 0, stream>>>(Hall, WfcT, b_fc, out);
}